// Round 1
// baseline (58.570 us; speedup 1.0000x reference)
//
#include <hip/hip_runtime.h>
#include <math.h>

// Problem dims (fixed by the reference)
#define F_  26
#define V_  100000
#define E_  16
#define B_  16384
#define ND_ 13
#define D_  4
#define H_  128
#define T_  8
#define IN_ 429      // F*E + ND
#define XPAD 432     // padded row stride for x tile (16B-aligned rows)
#define BB  32       // batch rows per block
#define FPAD 132     // padded stride for feat tile (avoid bank conflicts)

__global__ __launch_bounds__(256, 2)
void sb_fused_kernel(const int* __restrict__ sparse_ids,
                     const float* __restrict__ dense,
                     const int* __restrict__ domain_id,
                     const float* __restrict__ emb_tables,
                     const float* __restrict__ W_bottom,
                     const float* __restrict__ b_bottom,
                     const float* __restrict__ tower_W1,
                     const float* __restrict__ tower_b1,
                     const float* __restrict__ tower_W2,
                     const float* __restrict__ tower_b2,
                     float* __restrict__ out)
{
    __shared__ float x_lds[BB][XPAD];
    __shared__ float feat_lds[BB][FPAD];

    const int t  = threadIdx.x;
    const int r0 = blockIdx.x * BB;

    // ---------- Phase A: gather embeddings + dense into LDS ----------
    // 32 rows * 26 fields = 832 gather tasks; each copies 16 floats (64 B).
    for (int idx = t; idx < BB * F_; idx += 256) {
        const int row = idx / F_;
        const int f   = idx % F_;
        const int id  = sparse_ids[(r0 + row) * F_ + f];
        const float4* src = reinterpret_cast<const float4*>(
            emb_tables + ((size_t)f * V_ + (size_t)id) * E_);
        float4* dst = reinterpret_cast<float4*>(&x_lds[row][f * E_]);
        dst[0] = src[0];
        dst[1] = src[1];
        dst[2] = src[2];
        dst[3] = src[3];
    }
    // dense features -> columns 416..428
    for (int idx = t; idx < BB * ND_; idx += 256) {
        const int row = idx / ND_;
        const int j   = idx % ND_;
        x_lds[row][F_ * E_ + j] = dense[(r0 + row) * ND_ + j];
    }
    __syncthreads();

    // ---------- Phase B: bottom GEMM  feat = relu(X @ W + b) ----------
    // thread t -> column h = t & 127, row-group rg = t >> 7 (rows rg, rg+2, ...)
    const int h  = t & 127;
    const int rg = t >> 7;

    float acc[16];
#pragma unroll
    for (int k = 0; k < 16; ++k) acc[k] = 0.f;

    // main loop over i = 0..427 in steps of 4 (107 iters), tail i=428
    for (int i = 0; i < 428; i += 4) {
        const float w0 = W_bottom[(i + 0) * H_ + h];
        const float w1 = W_bottom[(i + 1) * H_ + h];
        const float w2 = W_bottom[(i + 2) * H_ + h];
        const float w3 = W_bottom[(i + 3) * H_ + h];
#pragma unroll
        for (int k = 0; k < 16; ++k) {
            const int r = rg + 2 * k;
            const float4 xv = *reinterpret_cast<const float4*>(&x_lds[r][i]);
            acc[k] = fmaf(xv.x, w0, acc[k]);
            acc[k] = fmaf(xv.y, w1, acc[k]);
            acc[k] = fmaf(xv.z, w2, acc[k]);
            acc[k] = fmaf(xv.w, w3, acc[k]);
        }
    }
    {
        const float w0 = W_bottom[428 * H_ + h];
#pragma unroll
        for (int k = 0; k < 16; ++k) {
            const int r = rg + 2 * k;
            acc[k] = fmaf(x_lds[r][428], w0, acc[k]);
        }
    }

    const float bias = b_bottom[h];
#pragma unroll
    for (int k = 0; k < 16; ++k) {
        const int r = rg + 2 * k;
        feat_lds[r][h] = fmaxf(acc[k] + bias, 0.f);
    }
    __syncthreads();

    // ---------- Phase C: per-domain tower + sigmoid ----------
    // thread t -> row = t>>3 (0..31), tower unit tt = t&7
    const int row = t >> 3;
    const int tt  = t & 7;
    const int d   = domain_id[r0 + row];

    const float* w1p = tower_W1 + ((size_t)d * H_) * T_ + tt;  // stride T_ over h
    float s = 0.f;
#pragma unroll 8
    for (int hh = 0; hh < H_; ++hh) {
        s = fmaf(feat_lds[row][hh], w1p[hh * T_], s);
    }
    s += tower_b1[d * T_ + tt];
    s = fmaxf(s, 0.f);            // relu on tower hidden
    s *= tower_W2[d * T_ + tt];   // weight for the final dot

    // reduce the 8 tower units (lanes tt=0..7 within the same wave)
    s += __shfl_xor(s, 1);
    s += __shfl_xor(s, 2);
    s += __shfl_xor(s, 4);

    if (tt == 0) {
        const float logit = s + tower_b2[d];
        out[r0 + row] = 1.f / (1.f + expf(-logit));
    }
}

extern "C" void kernel_launch(void* const* d_in, const int* in_sizes, int n_in,
                              void* d_out, int out_size, void* d_ws, size_t ws_size,
                              hipStream_t stream) {
    const int*   sparse_ids = (const int*)  d_in[0];
    const float* dense      = (const float*)d_in[1];
    const int*   domain_id  = (const int*)  d_in[2];
    const float* emb_tables = (const float*)d_in[3];
    const float* W_bottom   = (const float*)d_in[4];
    const float* b_bottom   = (const float*)d_in[5];
    const float* tower_W1   = (const float*)d_in[6];
    const float* tower_b1   = (const float*)d_in[7];
    const float* tower_W2   = (const float*)d_in[8];
    const float* tower_b2   = (const float*)d_in[9];
    float* out = (float*)d_out;

    const int grid = B_ / BB;  // 512 blocks
    sb_fused_kernel<<<grid, 256, 0, stream>>>(
        sparse_ids, dense, domain_id, emb_tables,
        W_bottom, b_bottom, tower_W1, tower_b1, tower_W2, tower_b2, out);
}

// Round 2
// 52.639 us; speedup vs baseline: 1.1127x; 1.1127x over previous
//
#include <hip/hip_runtime.h>
#include <math.h>

// Problem dims (fixed by the reference)
#define F_  26
#define V_  100000
#define E_  16
#define B_  16384
#define ND_ 13
#define D_  4
#define H_  128
#define T_  8
#define IN_ 429      // F*E + ND
#define XPAD 432     // padded row stride for x tile (16B-aligned rows)
#define BB  32       // batch rows per block
#define FPAD 132     // padded stride for feat tile (avoid bank conflicts)

#define FMA4(ACC, XS, WV)                \
    ACC.x = fmaf(XS, WV.x, ACC.x);       \
    ACC.y = fmaf(XS, WV.y, ACC.y);       \
    ACC.z = fmaf(XS, WV.z, ACC.z);       \
    ACC.w = fmaf(XS, WV.w, ACC.w);

__global__ __launch_bounds__(256, 2)
void sb_fused_kernel(const int* __restrict__ sparse_ids,
                     const float* __restrict__ dense,
                     const int* __restrict__ domain_id,
                     const float* __restrict__ emb_tables,
                     const float* __restrict__ W_bottom,
                     const float* __restrict__ b_bottom,
                     const float* __restrict__ tower_W1,
                     const float* __restrict__ tower_b1,
                     const float* __restrict__ tower_W2,
                     const float* __restrict__ tower_b2,
                     float* __restrict__ out)
{
    __shared__ float x_lds[BB][XPAD];
    __shared__ float feat_lds[BB][FPAD];

    const int t  = threadIdx.x;
    const int r0 = blockIdx.x * BB;

    // ---------- Phase A: gather embeddings + dense into LDS ----------
    // 32 rows * 26 fields * 4 float4s = 3328 tasks (13 iters of 256).
    // 4 consecutive lanes copy one 64B embedding row -> coalesced.
    for (int idx = t; idx < BB * F_ * 4; idx += 256) {
        const int q   = idx & 3;
        const int rf  = idx >> 2;          // row * F_ + f
        const int row = rf / F_;
        const int f   = rf - row * F_;
        const int id  = sparse_ids[(r0 + row) * F_ + f];
        const float4 v = reinterpret_cast<const float4*>(
            emb_tables + ((size_t)f * V_ + (size_t)id) * E_)[q];
        reinterpret_cast<float4*>(&x_lds[row][f * E_])[q] = v;
    }
    // dense features -> columns 416..428
    for (int idx = t; idx < BB * ND_; idx += 256) {
        const int row = idx / ND_;
        const int j   = idx - row * ND_;
        x_lds[row][F_ * E_ + j] = dense[(r0 + row) * ND_ + j];
    }
    __syncthreads();

    // ---------- Phase B: bottom GEMM  feat = relu(X @ W + b) ----------
    // 4x4 register tile: thread t -> cols [4*(t&31) .. +3], rows [4*(t>>5) .. +3]
    const int c0 = (t & 31) << 2;
    const int rb = (t >> 5) << 2;

    float4 acc0 = {0.f, 0.f, 0.f, 0.f};
    float4 acc1 = acc0, acc2 = acc0, acc3 = acc0;

    for (int k = 0; k < 428; k += 4) {
        const float4 x0 = *reinterpret_cast<const float4*>(&x_lds[rb + 0][k]);
        const float4 x1 = *reinterpret_cast<const float4*>(&x_lds[rb + 1][k]);
        const float4 x2 = *reinterpret_cast<const float4*>(&x_lds[rb + 2][k]);
        const float4 x3 = *reinterpret_cast<const float4*>(&x_lds[rb + 3][k]);
        const float4 w0 = *reinterpret_cast<const float4*>(&W_bottom[(k + 0) * H_ + c0]);
        const float4 w1 = *reinterpret_cast<const float4*>(&W_bottom[(k + 1) * H_ + c0]);
        const float4 w2 = *reinterpret_cast<const float4*>(&W_bottom[(k + 2) * H_ + c0]);
        const float4 w3 = *reinterpret_cast<const float4*>(&W_bottom[(k + 3) * H_ + c0]);

        FMA4(acc0, x0.x, w0) FMA4(acc0, x0.y, w1) FMA4(acc0, x0.z, w2) FMA4(acc0, x0.w, w3)
        FMA4(acc1, x1.x, w0) FMA4(acc1, x1.y, w1) FMA4(acc1, x1.z, w2) FMA4(acc1, x1.w, w3)
        FMA4(acc2, x2.x, w0) FMA4(acc2, x2.y, w1) FMA4(acc2, x2.z, w2) FMA4(acc2, x2.w, w3)
        FMA4(acc3, x3.x, w0) FMA4(acc3, x3.y, w1) FMA4(acc3, x3.z, w2) FMA4(acc3, x3.w, w3)
    }
    { // tail k = 428
        const float4 wt = *reinterpret_cast<const float4*>(&W_bottom[428 * H_ + c0]);
        FMA4(acc0, x_lds[rb + 0][428], wt)
        FMA4(acc1, x_lds[rb + 1][428], wt)
        FMA4(acc2, x_lds[rb + 2][428], wt)
        FMA4(acc3, x_lds[rb + 3][428], wt)
    }

    {
        const float4 bias = *reinterpret_cast<const float4*>(&b_bottom[c0]);
        float4 f;
        f.x = fmaxf(acc0.x + bias.x, 0.f); f.y = fmaxf(acc0.y + bias.y, 0.f);
        f.z = fmaxf(acc0.z + bias.z, 0.f); f.w = fmaxf(acc0.w + bias.w, 0.f);
        *reinterpret_cast<float4*>(&feat_lds[rb + 0][c0]) = f;
        f.x = fmaxf(acc1.x + bias.x, 0.f); f.y = fmaxf(acc1.y + bias.y, 0.f);
        f.z = fmaxf(acc1.z + bias.z, 0.f); f.w = fmaxf(acc1.w + bias.w, 0.f);
        *reinterpret_cast<float4*>(&feat_lds[rb + 1][c0]) = f;
        f.x = fmaxf(acc2.x + bias.x, 0.f); f.y = fmaxf(acc2.y + bias.y, 0.f);
        f.z = fmaxf(acc2.z + bias.z, 0.f); f.w = fmaxf(acc2.w + bias.w, 0.f);
        *reinterpret_cast<float4*>(&feat_lds[rb + 2][c0]) = f;
        f.x = fmaxf(acc3.x + bias.x, 0.f); f.y = fmaxf(acc3.y + bias.y, 0.f);
        f.z = fmaxf(acc3.z + bias.z, 0.f); f.w = fmaxf(acc3.w + bias.w, 0.f);
        *reinterpret_cast<float4*>(&feat_lds[rb + 3][c0]) = f;
    }
    __syncthreads();

    // ---------- Phase C: per-domain tower + sigmoid ----------
    // thread t -> row = t>>3 (0..31), tower unit tt = t&7
    const int row = t >> 3;
    const int tt  = t & 7;
    const int d   = domain_id[r0 + row];

    const float* w1p = tower_W1 + (size_t)d * H_ * T_ + tt;  // stride T_ over h
    float s = 0.f;
#pragma unroll
    for (int hh = 0; hh < H_; hh += 4) {
        const float4 fv = *reinterpret_cast<const float4*>(&feat_lds[row][hh]);
        s = fmaf(fv.x, w1p[(hh + 0) * T_], s);
        s = fmaf(fv.y, w1p[(hh + 1) * T_], s);
        s = fmaf(fv.z, w1p[(hh + 2) * T_], s);
        s = fmaf(fv.w, w1p[(hh + 3) * T_], s);
    }
    s += tower_b1[d * T_ + tt];
    s = fmaxf(s, 0.f);            // relu on tower hidden
    s *= tower_W2[d * T_ + tt];   // weight for the final dot

    // reduce the 8 tower units (lanes tt=0..7 within the same wave)
    s += __shfl_xor(s, 1);
    s += __shfl_xor(s, 2);
    s += __shfl_xor(s, 4);

    if (tt == 0) {
        const float logit = s + tower_b2[d];
        out[r0 + row] = 1.f / (1.f + expf(-logit));
    }
}

extern "C" void kernel_launch(void* const* d_in, const int* in_sizes, int n_in,
                              void* d_out, int out_size, void* d_ws, size_t ws_size,
                              hipStream_t stream) {
    const int*   sparse_ids = (const int*)  d_in[0];
    const float* dense      = (const float*)d_in[1];
    const int*   domain_id  = (const int*)  d_in[2];
    const float* emb_tables = (const float*)d_in[3];
    const float* W_bottom   = (const float*)d_in[4];
    const float* b_bottom   = (const float*)d_in[5];
    const float* tower_W1   = (const float*)d_in[6];
    const float* tower_b1   = (const float*)d_in[7];
    const float* tower_W2   = (const float*)d_in[8];
    const float* tower_b2   = (const float*)d_in[9];
    float* out = (float*)d_out;

    const int grid = B_ / BB;  // 512 blocks
    sb_fused_kernel<<<grid, 256, 0, stream>>>(
        sparse_ids, dense, domain_id, emb_tables,
        W_bottom, b_bottom, tower_W1, tower_b1, tower_W2, tower_b2, out);
}

// Round 3
// 32.503 us; speedup vs baseline: 1.8020x; 1.6195x over previous
//
#include <hip/hip_runtime.h>
#include <math.h>

// Problem dims (fixed by the reference)
#define F_  26
#define V_  100000
#define E_  16
#define B_  16384
#define ND_ 13
#define D_  4
#define H_  128
#define T_  8
#define KP  448      // K padded to 14*32
#define NKS 14       // K-steps of 32
#define XSTR 456     // x_lds row stride in bf16 (448 + 8 pad -> +4 banks/row)
#define BB  32       // batch rows per block
#define FPAD 132     // padded stride for feat tile

typedef short bf16x8 __attribute__((ext_vector_type(8)));
typedef float f32x4  __attribute__((ext_vector_type(4)));

__device__ __forceinline__ unsigned short f2bf(float f) {
    unsigned int u = __float_as_uint(f);
    u += 0x7FFF + ((u >> 16) & 1);   // RNE
    return (unsigned short)(u >> 16);
}

// ---------- prep: pack W_bottom into bf16 B-fragments; transpose tower_W1 ----------
// wsB layout: fragment (ks, n) is 64 lanes x 16B; lane l, elem j holds
//   W[ks*32 + (l>>4)*8 + j][n*16 + (l&15)]  (zero-padded past k=428)
__global__ __launch_bounds__(256)
void prep_kernel(const float* __restrict__ W_bottom,
                 const float* __restrict__ tower_W1,
                 unsigned short* __restrict__ wsB,
                 float* __restrict__ wsT)
{
    const int tid = blockIdx.x * 256 + threadIdx.x;
    if (tid < NKS * 8 * 64) {
        const int s   = tid >> 9;        // k-step
        const int rem = tid & 511;
        const int n   = rem >> 6;        // ntile
        const int l   = rem & 63;        // lane
        const int kbase = s * 32 + ((l >> 4) << 3);
        const int col   = (n << 4) + (l & 15);
        unsigned long long lo = 0, hi = 0;
#pragma unroll
        for (int j = 0; j < 4; ++j) {
            const int k = kbase + j;
            const float f = (k < 429) ? W_bottom[k * H_ + col] : 0.f;
            lo |= (unsigned long long)f2bf(f) << (16 * j);
        }
#pragma unroll
        for (int j = 0; j < 4; ++j) {
            const int k = kbase + 4 + j;
            const float f = (k < 429) ? W_bottom[k * H_ + col] : 0.f;
            hi |= (unsigned long long)f2bf(f) << (16 * j);
        }
        ulonglong2 pack; pack.x = lo; pack.y = hi;
        *reinterpret_cast<ulonglong2*>(wsB + (size_t)tid * 8) = pack;
    } else {
        const int t2 = tid - NKS * 8 * 64;
        if (t2 < D_ * T_ * H_) {
            const int d   = t2 >> 10;
            const int rem = t2 & 1023;
            const int tt  = rem >> 7;
            const int h   = rem & 127;
            wsT[(((d << 3) + tt) << 7) + h] = tower_W1[((d * H_) + h) * T_ + tt];
        }
    }
}

// ---------- fused main kernel ----------
__global__ __launch_bounds__(256, 2)
void sb_fused_kernel(const int* __restrict__ sparse_ids,
                     const float* __restrict__ dense,
                     const int* __restrict__ domain_id,
                     const float* __restrict__ emb_tables,
                     const float* __restrict__ b_bottom,
                     const float* __restrict__ tower_b1,
                     const float* __restrict__ tower_W2,
                     const float* __restrict__ tower_b2,
                     const unsigned short* __restrict__ wsB,
                     const float* __restrict__ wsT,
                     float* __restrict__ out)
{
    __shared__ unsigned short x_lds[BB][XSTR];   // bf16 activations
    __shared__ float feat_lds[BB][FPAD];

    const int t  = threadIdx.x;
    const int r0 = blockIdx.x * BB;

    // ---------- Phase A: gather embeddings (fp32 -> bf16) into LDS ----------
    // 32 rows * 26 fields * 4 quarters = 3328 tasks; 4 lanes share one 64B row.
    for (int idx = t; idx < BB * F_ * 4; idx += 256) {
        const int q   = idx & 3;
        const int rf  = idx >> 2;          // row * F_ + f
        const int row = rf / F_;
        const int f   = rf - row * F_;
        const int id  = sparse_ids[(r0 + row) * F_ + f];
        const float4 v = reinterpret_cast<const float4*>(
            emb_tables + ((size_t)f * V_ + (size_t)id) * E_)[q];
        ushort4 b;
        b.x = f2bf(v.x); b.y = f2bf(v.y); b.z = f2bf(v.z); b.w = f2bf(v.w);
        *reinterpret_cast<ushort4*>(&x_lds[row][(f << 4) + (q << 2)]) = b;
    }
    // dense -> cols 416..428 (bf16), zero-pad cols 429..447
    for (int idx = t; idx < BB * 32; idx += 256) {
        const int row = idx >> 5;
        const int c   = 416 + (idx & 31);
        x_lds[row][c] = (c < 429) ? f2bf(dense[(r0 + row) * ND_ + (c - 416)]) : 0;
    }
    __syncthreads();

    // ---------- Phase B: bottom GEMM via MFMA  feat = relu(X @ W + b) ----------
    // wave w handles ntiles {2w, 2w+1} (cols 32w..32w+31), both mtiles (rows 0..31)
    const int l   = t & 63;
    const int w   = t >> 6;
    const int lhi = l >> 4;        // 0..3
    const int llo = l & 15;

    f32x4 acc00 = {0.f,0.f,0.f,0.f};
    f32x4 acc01 = acc00, acc10 = acc00, acc11 = acc00;

    const bf16x8* wsBv = reinterpret_cast<const bf16x8*>(wsB);
#pragma unroll 2
    for (int ks = 0; ks < NKS; ++ks) {
        const int ko = ks * 32 + (lhi << 3);
        const bf16x8 a0 = *reinterpret_cast<const bf16x8*>(&x_lds[llo][ko]);
        const bf16x8 a1 = *reinterpret_cast<const bf16x8*>(&x_lds[16 + llo][ko]);
        const bf16x8 b0 = wsBv[((ks << 3) + (w << 1) + 0) * 64 + l];
        const bf16x8 b1 = wsBv[((ks << 3) + (w << 1) + 1) * 64 + l];
        acc00 = __builtin_amdgcn_mfma_f32_16x16x32_bf16(a0, b0, acc00, 0, 0, 0);
        acc01 = __builtin_amdgcn_mfma_f32_16x16x32_bf16(a0, b1, acc01, 0, 0, 0);
        acc10 = __builtin_amdgcn_mfma_f32_16x16x32_bf16(a1, b0, acc10, 0, 0, 0);
        acc11 = __builtin_amdgcn_mfma_f32_16x16x32_bf16(a1, b1, acc11, 0, 0, 0);
    }

    {   // epilogue: bias + relu -> feat_lds (fp32)
        const int c0 = ((w << 1) + 0) * 16 + llo;
        const int c1 = c0 + 16;
        const float bias0 = b_bottom[c0];
        const float bias1 = b_bottom[c1];
#pragma unroll
        for (int i = 0; i < 4; ++i) {
            const int r = (lhi << 2) + i;
            feat_lds[r][c0]      = fmaxf(acc00[i] + bias0, 0.f);
            feat_lds[r][c1]      = fmaxf(acc01[i] + bias1, 0.f);
            feat_lds[16 + r][c0] = fmaxf(acc10[i] + bias0, 0.f);
            feat_lds[16 + r][c1] = fmaxf(acc11[i] + bias1, 0.f);
        }
    }
    __syncthreads();

    // ---------- Phase C: per-domain tower + sigmoid ----------
    // thread t -> row = t>>3, tower unit tt = t&7; w1 read from transposed wsT
    const int row = t >> 3;
    const int tt  = t & 7;
    const int d   = domain_id[r0 + row];

    const float* wt = wsT + (((d << 3) + tt) << 7);   // [d][tt][0..127]
    float s = 0.f;
#pragma unroll 8
    for (int hh = 0; hh < H_; hh += 4) {
        const float4 fv = *reinterpret_cast<const float4*>(&feat_lds[row][hh]);
        const float4 wv = *reinterpret_cast<const float4*>(&wt[hh]);
        s = fmaf(fv.x, wv.x, s);
        s = fmaf(fv.y, wv.y, s);
        s = fmaf(fv.z, wv.z, s);
        s = fmaf(fv.w, wv.w, s);
    }
    s += tower_b1[d * T_ + tt];
    s = fmaxf(s, 0.f);            // relu on tower hidden
    s *= tower_W2[d * T_ + tt];   // weight for the final dot

    s += __shfl_xor(s, 1);
    s += __shfl_xor(s, 2);
    s += __shfl_xor(s, 4);

    if (tt == 0) {
        const float logit = s + tower_b2[d];
        out[r0 + row] = 1.f / (1.f + expf(-logit));
    }
}

extern "C" void kernel_launch(void* const* d_in, const int* in_sizes, int n_in,
                              void* d_out, int out_size, void* d_ws, size_t ws_size,
                              hipStream_t stream) {
    const int*   sparse_ids = (const int*)  d_in[0];
    const float* dense      = (const float*)d_in[1];
    const int*   domain_id  = (const int*)  d_in[2];
    const float* emb_tables = (const float*)d_in[3];
    const float* W_bottom   = (const float*)d_in[4];
    const float* b_bottom   = (const float*)d_in[5];
    const float* tower_W1   = (const float*)d_in[6];
    const float* tower_b1   = (const float*)d_in[7];
    const float* tower_W2   = (const float*)d_in[8];
    const float* tower_b2   = (const float*)d_in[9];
    float* out = (float*)d_out;

    unsigned short* wsB = (unsigned short*)d_ws;               // 114,688 B
    float*          wsT = (float*)((char*)d_ws + 131072);      // 16,384 B

    // prep: 7168 (B-pack) + 4096 (tower transpose) threads
    prep_kernel<<<(NKS * 8 * 64 + D_ * T_ * H_ + 255) / 256, 256, 0, stream>>>(
        W_bottom, tower_W1, wsB, wsT);

    sb_fused_kernel<<<B_ / BB, 256, 0, stream>>>(
        sparse_ids, dense, domain_id, emb_tables,
        b_bottom, tower_b1, tower_W2, tower_b2, wsB, wsT, out);
}

// Round 4
// 27.981 us; speedup vs baseline: 2.0932x; 1.1616x over previous
//
#include <hip/hip_runtime.h>
#include <math.h>

// Problem dims (fixed by the reference)
#define F_  26
#define V_  100000
#define E_  16
#define B_  16384
#define ND_ 13
#define D_  4
#define H_  128
#define T_  8
#define KP  448      // K padded to 14*32
#define NKS 14       // K-steps of 32
#define XSTR 456     // x_lds row stride in bf16 (448 + 8 pad)
#define FSTR 136     // feat_lds row stride in bf16 (128 + 8 pad)
#define BB  32       // batch rows per block

typedef short bf16x8 __attribute__((ext_vector_type(8)));
typedef float f32x4  __attribute__((ext_vector_type(4)));

__device__ __forceinline__ unsigned short f2bf(float f) {
    unsigned int u = __float_as_uint(f);
    u += 0x7FFF + ((u >> 16) & 1);   // RNE
    return (unsigned short)(u >> 16);
}

// ---------- prep: pack W_bottom + tower_W1 into bf16 MFMA B-fragments ----------
// wsB: fragment (ks, n): lane l elem j = W[ks*32 + (l>>4)*8 + j][n*16 + (l&15)]
// wsT1: fragment (ks2, n2): lane l elem j = W1_all[ks2*32 + (l>>4)*8 + j][n2*16 + (l&15)]
//   where W1_all[h][d*8+tt] = tower_W1[d][h][tt]
__global__ __launch_bounds__(256)
void prep_kernel(const float* __restrict__ W_bottom,
                 const float* __restrict__ tower_W1,
                 unsigned short* __restrict__ wsB,
                 unsigned short* __restrict__ wsT1)
{
    const int tid = blockIdx.x * 256 + threadIdx.x;
    if (tid < NKS * 8 * 64) {
        const int s   = tid >> 9;        // k-step
        const int rem = tid & 511;
        const int n   = rem >> 6;        // ntile
        const int l   = rem & 63;        // lane
        const int kbase = s * 32 + ((l >> 4) << 3);
        const int col   = (n << 4) + (l & 15);
        unsigned long long lo = 0, hi = 0;
#pragma unroll
        for (int j = 0; j < 4; ++j) {
            const int k = kbase + j;
            const float f = (k < 429) ? W_bottom[k * H_ + col] : 0.f;
            lo |= (unsigned long long)f2bf(f) << (16 * j);
        }
#pragma unroll
        for (int j = 0; j < 4; ++j) {
            const int k = kbase + 4 + j;
            const float f = (k < 429) ? W_bottom[k * H_ + col] : 0.f;
            hi |= (unsigned long long)f2bf(f) << (16 * j);
        }
        ulonglong2 pack; pack.x = lo; pack.y = hi;
        *reinterpret_cast<ulonglong2*>(wsB + (size_t)tid * 8) = pack;
    } else {
        const int t2 = tid - NKS * 8 * 64;
        if (t2 < 8 * 64) {               // 4 ks2 x 2 n2 fragments
            const int frag = t2 >> 6;    // ks2*2 + n2
            const int l    = t2 & 63;
            const int ks2  = frag >> 1;
            const int n2   = frag & 1;
            const int kbase = ks2 * 32 + ((l >> 4) << 3);
            const int col   = (n2 << 4) + (l & 15);
            const int d     = col >> 3;
            const int tt    = col & 7;
            unsigned long long lo = 0, hi = 0;
#pragma unroll
            for (int j = 0; j < 4; ++j) {
                const int h = kbase + j;
                lo |= (unsigned long long)f2bf(tower_W1[((d << 7) + h) * T_ + tt]) << (16 * j);
            }
#pragma unroll
            for (int j = 0; j < 4; ++j) {
                const int h = kbase + 4 + j;
                hi |= (unsigned long long)f2bf(tower_W1[((d << 7) + h) * T_ + tt]) << (16 * j);
            }
            ulonglong2 pack; pack.x = lo; pack.y = hi;
            *reinterpret_cast<ulonglong2*>(wsT1 + (size_t)t2 * 8) = pack;
        }
    }
}

// ---------- fused main kernel ----------
__global__ __launch_bounds__(256, 4)
void sb_fused_kernel(const int* __restrict__ sparse_ids,
                     const float* __restrict__ dense,
                     const int* __restrict__ domain_id,
                     const float* __restrict__ emb_tables,
                     const float* __restrict__ b_bottom,
                     const float* __restrict__ tower_b1,
                     const float* __restrict__ tower_W2,
                     const float* __restrict__ tower_b2,
                     const unsigned short* __restrict__ wsB,
                     const unsigned short* __restrict__ wsT1,
                     float* __restrict__ out)
{
    __shared__ unsigned short x_lds[BB][XSTR];     // 29,184 B
    __shared__ unsigned short feat_lds[BB][FSTR];  //  8,704 B

    const int t  = threadIdx.x;
    const int r0 = blockIdx.x * BB;

    // ---------- Phase A: gather embeddings (fp32 -> bf16) into LDS ----------
    for (int idx = t; idx < BB * F_ * 4; idx += 256) {
        const int q   = idx & 3;
        const int rf  = idx >> 2;          // row * F_ + f
        const int row = rf / F_;
        const int f   = rf - row * F_;
        const int id  = sparse_ids[(r0 + row) * F_ + f];
        const float4 v = reinterpret_cast<const float4*>(
            emb_tables + ((size_t)f * V_ + (size_t)id) * E_)[q];
        ushort4 b;
        b.x = f2bf(v.x); b.y = f2bf(v.y); b.z = f2bf(v.z); b.w = f2bf(v.w);
        *reinterpret_cast<ushort4*>(&x_lds[row][(f << 4) + (q << 2)]) = b;
    }
    // dense -> cols 416..428 (bf16), zero-pad cols 429..447
    for (int idx = t; idx < BB * 32; idx += 256) {
        const int row = idx >> 5;
        const int c   = 416 + (idx & 31);
        x_lds[row][c] = (c < 429) ? f2bf(dense[(r0 + row) * ND_ + (c - 416)]) : 0;
    }
    __syncthreads();

    // ---------- Phase B: bottom GEMM via MFMA  feat = relu(X @ W + b) ----------
    const int l   = t & 63;
    const int w   = t >> 6;
    const int lhi = l >> 4;        // 0..3
    const int llo = l & 15;

    f32x4 acc00 = {0.f,0.f,0.f,0.f};
    f32x4 acc01 = acc00, acc10 = acc00, acc11 = acc00;

    const bf16x8* wsBv = reinterpret_cast<const bf16x8*>(wsB);
#pragma unroll 2
    for (int ks = 0; ks < NKS; ++ks) {
        const int ko = ks * 32 + (lhi << 3);
        const bf16x8 a0 = *reinterpret_cast<const bf16x8*>(&x_lds[llo][ko]);
        const bf16x8 a1 = *reinterpret_cast<const bf16x8*>(&x_lds[16 + llo][ko]);
        const bf16x8 b0 = wsBv[((ks << 3) + (w << 1) + 0) * 64 + l];
        const bf16x8 b1 = wsBv[((ks << 3) + (w << 1) + 1) * 64 + l];
        acc00 = __builtin_amdgcn_mfma_f32_16x16x32_bf16(a0, b0, acc00, 0, 0, 0);
        acc01 = __builtin_amdgcn_mfma_f32_16x16x32_bf16(a0, b1, acc01, 0, 0, 0);
        acc10 = __builtin_amdgcn_mfma_f32_16x16x32_bf16(a1, b0, acc10, 0, 0, 0);
        acc11 = __builtin_amdgcn_mfma_f32_16x16x32_bf16(a1, b1, acc11, 0, 0, 0);
    }

    {   // epilogue: bias + relu -> feat_lds (bf16, A-fragment-friendly layout)
        const int c0 = ((w << 1) + 0) * 16 + llo;
        const int c1 = c0 + 16;
        const float bias0 = b_bottom[c0];
        const float bias1 = b_bottom[c1];
#pragma unroll
        for (int i = 0; i < 4; ++i) {
            const int r = (lhi << 2) + i;
            feat_lds[r][c0]      = f2bf(fmaxf(acc00[i] + bias0, 0.f));
            feat_lds[r][c1]      = f2bf(fmaxf(acc01[i] + bias1, 0.f));
            feat_lds[16 + r][c0] = f2bf(fmaxf(acc10[i] + bias0, 0.f));
            feat_lds[16 + r][c1] = f2bf(fmaxf(acc11[i] + bias1, 0.f));
        }
    }
    __syncthreads();

    // ---------- Phase C: tower via MFMA over all 4 domains ----------
    // h_all[32 rows][32 cols], col = d*8 + tt.  wave w: mtile = w>>1, ntile = w&1
    const int mt = w >> 1;
    const int nt = w & 1;
    f32x4 acc = {0.f,0.f,0.f,0.f};
    const bf16x8* wsT1v = reinterpret_cast<const bf16x8*>(wsT1);
#pragma unroll
    for (int ks2 = 0; ks2 < 4; ++ks2) {
        const bf16x8 a = *reinterpret_cast<const bf16x8*>(
            &feat_lds[(mt << 4) + llo][(ks2 << 5) + (lhi << 3)]);
        const bf16x8 b = wsT1v[((ks2 << 1) + nt) * 64 + l];
        acc = __builtin_amdgcn_mfma_f32_16x16x32_bf16(a, b, acc, 0, 0, 0);
    }
    const int col    = (nt << 4) + llo;    // global tower col = d*8 + tt
    const float b1v  = tower_b1[col];
    const float w2v  = tower_W2[col];
    const int  dlane = (nt << 1) + (llo >> 3);
    const bool writer = ((llo & 7) == 0);
#pragma unroll
    for (int i = 0; i < 4; ++i) {
        float v = fmaxf(acc[i] + b1v, 0.f) * w2v;
        v += __shfl_xor(v, 1);
        v += __shfl_xor(v, 2);
        v += __shfl_xor(v, 4);
        if (writer) {
            const int r   = (mt << 4) + (lhi << 2) + i;
            const int d_r = domain_id[r0 + r];
            if (d_r == dlane) {
                out[r0 + r] = 1.f / (1.f + expf(-(v + tower_b2[d_r])));
            }
        }
    }
}

extern "C" void kernel_launch(void* const* d_in, const int* in_sizes, int n_in,
                              void* d_out, int out_size, void* d_ws, size_t ws_size,
                              hipStream_t stream) {
    const int*   sparse_ids = (const int*)  d_in[0];
    const float* dense      = (const float*)d_in[1];
    const int*   domain_id  = (const int*)  d_in[2];
    const float* emb_tables = (const float*)d_in[3];
    const float* W_bottom   = (const float*)d_in[4];
    const float* b_bottom   = (const float*)d_in[5];
    const float* tower_W1   = (const float*)d_in[6];
    const float* tower_b1   = (const float*)d_in[7];
    const float* tower_W2   = (const float*)d_in[8];
    const float* tower_b2   = (const float*)d_in[9];
    float* out = (float*)d_out;

    unsigned short* wsB  = (unsigned short*)d_ws;               // 114,688 B
    unsigned short* wsT1 = (unsigned short*)((char*)d_ws + 131072);  // 8,192 B

    // prep: 7168 (W_bottom pack) + 512 (tower_W1 pack) threads
    prep_kernel<<<(NKS * 8 * 64 + 8 * 64 + 255) / 256, 256, 0, stream>>>(
        W_bottom, tower_W1, wsB, wsT1);

    sb_fused_kernel<<<B_ / BB, 256, 0, stream>>>(
        sparse_ids, dense, domain_id, emb_tables,
        b_bottom, tower_b1, tower_W2, tower_b2, wsB, wsT1, out);
}

// Round 5
// 26.565 us; speedup vs baseline: 2.2047x; 1.0533x over previous
//
#include <hip/hip_runtime.h>
#include <math.h>

// Problem dims (fixed by the reference)
#define F_  26
#define V_  100000
#define E_  16
#define B_  16384
#define ND_ 13
#define D_  4
#define H_  128
#define T_  8
#define KP  448      // K padded to 14*32
#define NKS 14       // K-steps of 32
#define XSTR 456     // x_lds row stride in bf16 (448 + 8 pad)
#define FSTR 136     // feat_lds row stride in bf16 (128 + 8 pad)
#define BB  32       // batch rows per block
#define NT  512      // threads per block (8 waves -> 16 waves/CU at 2 blocks/CU)

typedef short bf16x8 __attribute__((ext_vector_type(8)));
typedef float f32x4  __attribute__((ext_vector_type(4)));

__device__ __forceinline__ unsigned short f2bf(float f) {
    unsigned int u = __float_as_uint(f);
    u += 0x7FFF + ((u >> 16) & 1);   // RNE
    return (unsigned short)(u >> 16);
}

// ---------- prep: pack W_bottom + tower_W1 into bf16 MFMA B-fragments ----------
// wsB: fragment (ks, n): lane l elem j = W[ks*32 + (l>>4)*8 + j][n*16 + (l&15)]
// wsT1: fragment (ks2, n2): lane l elem j = W1_all[ks2*32 + (l>>4)*8 + j][n2*16 + (l&15)]
//   where W1_all[h][d*8+tt] = tower_W1[d][h][tt]
__global__ __launch_bounds__(256)
void prep_kernel(const float* __restrict__ W_bottom,
                 const float* __restrict__ tower_W1,
                 unsigned short* __restrict__ wsB,
                 unsigned short* __restrict__ wsT1)
{
    const int tid = blockIdx.x * 256 + threadIdx.x;
    if (tid < NKS * 8 * 64) {
        const int s   = tid >> 9;        // k-step
        const int rem = tid & 511;
        const int n   = rem >> 6;        // ntile
        const int l   = rem & 63;        // lane
        const int kbase = s * 32 + ((l >> 4) << 3);
        const int col   = (n << 4) + (l & 15);
        unsigned long long lo = 0, hi = 0;
#pragma unroll
        for (int j = 0; j < 4; ++j) {
            const int k = kbase + j;
            const float f = (k < 429) ? W_bottom[k * H_ + col] : 0.f;
            lo |= (unsigned long long)f2bf(f) << (16 * j);
        }
#pragma unroll
        for (int j = 0; j < 4; ++j) {
            const int k = kbase + 4 + j;
            const float f = (k < 429) ? W_bottom[k * H_ + col] : 0.f;
            hi |= (unsigned long long)f2bf(f) << (16 * j);
        }
        ulonglong2 pack; pack.x = lo; pack.y = hi;
        *reinterpret_cast<ulonglong2*>(wsB + (size_t)tid * 8) = pack;
    } else {
        const int t2 = tid - NKS * 8 * 64;
        if (t2 < 8 * 64) {               // 4 ks2 x 2 n2 fragments
            const int frag = t2 >> 6;    // ks2*2 + n2
            const int l    = t2 & 63;
            const int ks2  = frag >> 1;
            const int n2   = frag & 1;
            const int kbase = ks2 * 32 + ((l >> 4) << 3);
            const int col   = (n2 << 4) + (l & 15);
            const int d     = col >> 3;
            const int tt    = col & 7;
            unsigned long long lo = 0, hi = 0;
#pragma unroll
            for (int j = 0; j < 4; ++j) {
                const int h = kbase + j;
                lo |= (unsigned long long)f2bf(tower_W1[((d << 7) + h) * T_ + tt]) << (16 * j);
            }
#pragma unroll
            for (int j = 0; j < 4; ++j) {
                const int h = kbase + 4 + j;
                hi |= (unsigned long long)f2bf(tower_W1[((d << 7) + h) * T_ + tt]) << (16 * j);
            }
            ulonglong2 pack; pack.x = lo; pack.y = hi;
            *reinterpret_cast<ulonglong2*>(wsT1 + (size_t)t2 * 8) = pack;
        }
    }
}

// ---------- fused main kernel ----------
__global__ __launch_bounds__(NT, 4)
void sb_fused_kernel(const int* __restrict__ sparse_ids,
                     const float* __restrict__ dense,
                     const int* __restrict__ domain_id,
                     const float* __restrict__ emb_tables,
                     const float* __restrict__ b_bottom,
                     const float* __restrict__ tower_b1,
                     const float* __restrict__ tower_W2,
                     const float* __restrict__ tower_b2,
                     const unsigned short* __restrict__ wsB,
                     const unsigned short* __restrict__ wsT1,
                     float* __restrict__ out)
{
    __shared__ unsigned short x_lds[BB][XSTR];     // 29,184 B
    __shared__ unsigned short feat_lds[BB][FSTR];  //  8,704 B

    const int t  = threadIdx.x;
    const int r0 = blockIdx.x * BB;

    // ---------- Phase A: gather embeddings (fp32 -> bf16) into LDS ----------
    // 32 rows * 26 fields * 4 quarters = 3328 tasks; 4 lanes share one 64B row.
    for (int idx = t; idx < BB * F_ * 4; idx += NT) {
        const int q   = idx & 3;
        const int rf  = idx >> 2;          // row * F_ + f
        const int row = rf / F_;
        const int f   = rf - row * F_;
        const int id  = sparse_ids[(r0 + row) * F_ + f];
        const float4 v = reinterpret_cast<const float4*>(
            emb_tables + ((size_t)f * V_ + (size_t)id) * E_)[q];
        ushort4 b;
        b.x = f2bf(v.x); b.y = f2bf(v.y); b.z = f2bf(v.z); b.w = f2bf(v.w);
        *reinterpret_cast<ushort4*>(&x_lds[row][(f << 4) + (q << 2)]) = b;
    }
    // dense -> cols 416..428 (bf16), zero-pad cols 429..447
    for (int idx = t; idx < BB * 32; idx += NT) {
        const int row = idx >> 5;
        const int c   = 416 + (idx & 31);
        x_lds[row][c] = (c < 429) ? f2bf(dense[(r0 + row) * ND_ + (c - 416)]) : 0;
    }
    __syncthreads();

    // ---------- Phase B: bottom GEMM via MFMA  feat = relu(X @ W + b) ----------
    // 8 waves: wave w owns ntile w (cols 16w..16w+15), both mtiles (rows 0..31)
    const int l   = t & 63;
    const int w   = t >> 6;        // 0..7
    const int lhi = l >> 4;        // 0..3
    const int llo = l & 15;

    f32x4 acc0 = {0.f,0.f,0.f,0.f};
    f32x4 acc1 = acc0;

    const bf16x8* wsBv = reinterpret_cast<const bf16x8*>(wsB);
#pragma unroll 2
    for (int ks = 0; ks < NKS; ++ks) {
        const int ko = ks * 32 + (lhi << 3);
        const bf16x8 a0 = *reinterpret_cast<const bf16x8*>(&x_lds[llo][ko]);
        const bf16x8 a1 = *reinterpret_cast<const bf16x8*>(&x_lds[16 + llo][ko]);
        const bf16x8 b  = wsBv[((ks << 3) + w) * 64 + l];
        acc0 = __builtin_amdgcn_mfma_f32_16x16x32_bf16(a0, b, acc0, 0, 0, 0);
        acc1 = __builtin_amdgcn_mfma_f32_16x16x32_bf16(a1, b, acc1, 0, 0, 0);
    }

    {   // epilogue: bias + relu -> feat_lds (bf16, A-fragment-friendly layout)
        const int c = (w << 4) + llo;
        const float bias = b_bottom[c];
#pragma unroll
        for (int i = 0; i < 4; ++i) {
            const int r = (lhi << 2) + i;
            feat_lds[r][c]      = f2bf(fmaxf(acc0[i] + bias, 0.f));
            feat_lds[16 + r][c] = f2bf(fmaxf(acc1[i] + bias, 0.f));
        }
    }
    __syncthreads();

    // ---------- Phase C: tower via MFMA over all 4 domains (waves 0..3) ----------
    // h_all[32 rows][32 cols], col = d*8 + tt.  wave w: mtile = w>>1, ntile = w&1
    if (w < 4) {
        const int mt = w >> 1;
        const int nt = w & 1;
        f32x4 acc = {0.f,0.f,0.f,0.f};
        const bf16x8* wsT1v = reinterpret_cast<const bf16x8*>(wsT1);
#pragma unroll
        for (int ks2 = 0; ks2 < 4; ++ks2) {
            const bf16x8 a = *reinterpret_cast<const bf16x8*>(
                &feat_lds[(mt << 4) + llo][(ks2 << 5) + (lhi << 3)]);
            const bf16x8 b = wsT1v[((ks2 << 1) + nt) * 64 + l];
            acc = __builtin_amdgcn_mfma_f32_16x16x32_bf16(a, b, acc, 0, 0, 0);
        }
        const int col    = (nt << 4) + llo;    // global tower col = d*8 + tt
        const float b1v  = tower_b1[col];
        const float w2v  = tower_W2[col];
        const int  dlane = (nt << 1) + (llo >> 3);
        const bool writer = ((llo & 7) == 0);
#pragma unroll
        for (int i = 0; i < 4; ++i) {
            float v = fmaxf(acc[i] + b1v, 0.f) * w2v;
            v += __shfl_xor(v, 1);
            v += __shfl_xor(v, 2);
            v += __shfl_xor(v, 4);
            if (writer) {
                const int r   = (mt << 4) + (lhi << 2) + i;
                const int d_r = domain_id[r0 + r];
                if (d_r == dlane) {
                    out[r0 + r] = 1.f / (1.f + expf(-(v + tower_b2[d_r])));
                }
            }
        }
    }
}

extern "C" void kernel_launch(void* const* d_in, const int* in_sizes, int n_in,
                              void* d_out, int out_size, void* d_ws, size_t ws_size,
                              hipStream_t stream) {
    const int*   sparse_ids = (const int*)  d_in[0];
    const float* dense      = (const float*)d_in[1];
    const int*   domain_id  = (const int*)  d_in[2];
    const float* emb_tables = (const float*)d_in[3];
    const float* W_bottom   = (const float*)d_in[4];
    const float* b_bottom   = (const float*)d_in[5];
    const float* tower_W1   = (const float*)d_in[6];
    const float* tower_b1   = (const float*)d_in[7];
    const float* tower_W2   = (const float*)d_in[8];
    const float* tower_b2   = (const float*)d_in[9];
    float* out = (float*)d_out;

    unsigned short* wsB  = (unsigned short*)d_ws;                    // 114,688 B
    unsigned short* wsT1 = (unsigned short*)((char*)d_ws + 131072);  //   8,192 B

    // prep: 7168 (W_bottom pack) + 512 (tower_W1 pack) threads
    prep_kernel<<<(NKS * 8 * 64 + 8 * 64 + 255) / 256, 256, 0, stream>>>(
        W_bottom, tower_W1, wsB, wsT1);

    sb_fused_kernel<<<B_ / BB, NT, 0, stream>>>(
        sparse_ids, dense, domain_id, emb_tables,
        b_bottom, tower_b1, tower_W2, tower_b2, wsB, wsT1, out);
}

// Round 6
// 25.484 us; speedup vs baseline: 2.2983x; 1.0424x over previous
//
#include <hip/hip_runtime.h>
#include <math.h>

// Problem dims (fixed by the reference)
#define F_  26
#define V_  100000
#define E_  16
#define B_  16384
#define ND_ 13
#define D_  4
#define H_  128
#define T_  8
#define KP  448      // K padded to 14*32
#define NKS 14       // K-steps of 32
#define XSTR 456     // x_lds row stride in bf16 (448 + 8 pad)
#define FSTR 136     // feat_lds row stride in bf16 (128 + 8 pad)
#define BB  32       // batch rows per block
#define NT  512      // threads per block
#define NGT 7        // gather tasks per thread (ceil(3328/512))

typedef short bf16x8 __attribute__((ext_vector_type(8)));
typedef float f32x4  __attribute__((ext_vector_type(4)));

__device__ __forceinline__ unsigned short f2bf(float f) {
    unsigned int u = __float_as_uint(f);
    u += 0x7FFF + ((u >> 16) & 1);   // RNE
    return (unsigned short)(u >> 16);
}

// ---------- prep: pack W_bottom + tower_W1 into bf16 MFMA B-fragments ----------
// wsB: fragment (ks, n): lane l elem j = W[ks*32 + (l>>4)*8 + j][n*16 + (l&15)]
// wsT1: fragment (ks2, n2): lane l elem j = W1_all[ks2*32 + (l>>4)*8 + j][n2*16 + (l&15)]
//   where W1_all[h][d*8+tt] = tower_W1[d][h][tt]
__global__ __launch_bounds__(256)
void prep_kernel(const float* __restrict__ W_bottom,
                 const float* __restrict__ tower_W1,
                 unsigned short* __restrict__ wsB,
                 unsigned short* __restrict__ wsT1)
{
    const int tid = blockIdx.x * 256 + threadIdx.x;
    if (tid < NKS * 8 * 64) {
        const int s   = tid >> 9;        // k-step
        const int rem = tid & 511;
        const int n   = rem >> 6;        // ntile
        const int l   = rem & 63;        // lane
        const int kbase = s * 32 + ((l >> 4) << 3);
        const int col   = (n << 4) + (l & 15);
        unsigned long long lo = 0, hi = 0;
#pragma unroll
        for (int j = 0; j < 4; ++j) {
            const int k = kbase + j;
            const float f = (k < 429) ? W_bottom[k * H_ + col] : 0.f;
            lo |= (unsigned long long)f2bf(f) << (16 * j);
        }
#pragma unroll
        for (int j = 0; j < 4; ++j) {
            const int k = kbase + 4 + j;
            const float f = (k < 429) ? W_bottom[k * H_ + col] : 0.f;
            hi |= (unsigned long long)f2bf(f) << (16 * j);
        }
        ulonglong2 pack; pack.x = lo; pack.y = hi;
        *reinterpret_cast<ulonglong2*>(wsB + (size_t)tid * 8) = pack;
    } else {
        const int t2 = tid - NKS * 8 * 64;
        if (t2 < 8 * 64) {               // 4 ks2 x 2 n2 fragments
            const int frag = t2 >> 6;    // ks2*2 + n2
            const int l    = t2 & 63;
            const int ks2  = frag >> 1;
            const int n2   = frag & 1;
            const int kbase = ks2 * 32 + ((l >> 4) << 3);
            const int col   = (n2 << 4) + (l & 15);
            const int d     = col >> 3;
            const int tt    = col & 7;
            unsigned long long lo = 0, hi = 0;
#pragma unroll
            for (int j = 0; j < 4; ++j) {
                const int h = kbase + j;
                lo |= (unsigned long long)f2bf(tower_W1[((d << 7) + h) * T_ + tt]) << (16 * j);
            }
#pragma unroll
            for (int j = 0; j < 4; ++j) {
                const int h = kbase + 4 + j;
                hi |= (unsigned long long)f2bf(tower_W1[((d << 7) + h) * T_ + tt]) << (16 * j);
            }
            ulonglong2 pack; pack.x = lo; pack.y = hi;
            *reinterpret_cast<ulonglong2*>(wsT1 + (size_t)t2 * 8) = pack;
        }
    }
}

// ---------- fused main kernel ----------
__global__ __launch_bounds__(NT, 4)
void sb_fused_kernel(const int* __restrict__ sparse_ids,
                     const float* __restrict__ dense,
                     const int* __restrict__ domain_id,
                     const float* __restrict__ emb_tables,
                     const float* __restrict__ b_bottom,
                     const float* __restrict__ tower_b1,
                     const float* __restrict__ tower_W2,
                     const float* __restrict__ tower_b2,
                     const unsigned short* __restrict__ wsB,
                     const unsigned short* __restrict__ wsT1,
                     float* __restrict__ out)
{
    __shared__ unsigned short x_lds[BB][XSTR];     // 29,184 B
    __shared__ unsigned short feat_lds[BB][FSTR];  //  8,704 B

    const int t  = threadIdx.x;
    const int r0 = blockIdx.x * BB;

    // ---------- Phase A: hand-pipelined gather (fp32 -> bf16) into LDS ----------
    // 32 rows * 26 fields * 4 quarters = 3328 float4-tasks; 4 lanes share one row.
    // Step 1: issue ALL id loads. Step 2: issue ALL float4 gathers (7 outstanding
    // HBM requests per thread). Step 3: convert + LDS write.
    {
        int    ldsoff[NGT];
        int    id_[NGT];
        int    fq_[NGT];
        float4 v_[NGT];
#pragma unroll
        for (int it = 0; it < NGT; ++it) {
            const int idx = t + (it << 9);
            if (idx < BB * F_ * 4) {
                const int q   = idx & 3;
                const int rf  = idx >> 2;          // row * F_ + f
                const int row = rf / F_;
                const int f   = rf - row * F_;
                id_[it]    = sparse_ids[(r0 + row) * F_ + f];
                fq_[it]    = (f << 2) | q;
                ldsoff[it] = row * XSTR + (f << 4) + (q << 2);
            }
        }
#pragma unroll
        for (int it = 0; it < NGT; ++it) {
            const int idx = t + (it << 9);
            if (idx < BB * F_ * 4) {
                const int f = fq_[it] >> 2;
                const int q = fq_[it] & 3;
                v_[it] = *reinterpret_cast<const float4*>(
                    emb_tables + ((size_t)f * V_ + (size_t)id_[it]) * E_ + (q << 2));
            }
        }
#pragma unroll
        for (int it = 0; it < NGT; ++it) {
            const int idx = t + (it << 9);
            if (idx < BB * F_ * 4) {
                ushort4 b;
                b.x = f2bf(v_[it].x); b.y = f2bf(v_[it].y);
                b.z = f2bf(v_[it].z); b.w = f2bf(v_[it].w);
                *reinterpret_cast<ushort4*>(&x_lds[0][0] + ldsoff[it]) = b;
            }
        }
    }
    // dense -> cols 416..428 (bf16), zero-pad cols 429..447 (2 tasks/thread)
#pragma unroll
    for (int it = 0; it < 2; ++it) {
        const int idx = t + (it << 9);
        const int row = idx >> 5;
        const int c   = 416 + (idx & 31);
        x_lds[row][c] = (c < 429) ? f2bf(dense[(r0 + row) * ND_ + (c - 416)]) : 0;
    }
    __syncthreads();

    // ---------- Phase B: bottom GEMM via MFMA  feat = relu(X @ W + b) ----------
    // 8 waves: wave w owns ntile w (cols 16w..16w+15), both mtiles (rows 0..31)
    const int l   = t & 63;
    const int w   = t >> 6;        // 0..7
    const int lhi = l >> 4;        // 0..3
    const int llo = l & 15;

    f32x4 acc0 = {0.f,0.f,0.f,0.f};
    f32x4 acc1 = acc0;

    const bf16x8* wsBv = reinterpret_cast<const bf16x8*>(wsB);
#pragma unroll 2
    for (int ks = 0; ks < NKS; ++ks) {
        const int ko = ks * 32 + (lhi << 3);
        const bf16x8 a0 = *reinterpret_cast<const bf16x8*>(&x_lds[llo][ko]);
        const bf16x8 a1 = *reinterpret_cast<const bf16x8*>(&x_lds[16 + llo][ko]);
        const bf16x8 b  = wsBv[((ks << 3) + w) * 64 + l];
        acc0 = __builtin_amdgcn_mfma_f32_16x16x32_bf16(a0, b, acc0, 0, 0, 0);
        acc1 = __builtin_amdgcn_mfma_f32_16x16x32_bf16(a1, b, acc1, 0, 0, 0);
    }

    {   // epilogue: bias + relu -> feat_lds (bf16, A-fragment-friendly layout)
        const int c = (w << 4) + llo;
        const float bias = b_bottom[c];
#pragma unroll
        for (int i = 0; i < 4; ++i) {
            const int r = (lhi << 2) + i;
            feat_lds[r][c]      = f2bf(fmaxf(acc0[i] + bias, 0.f));
            feat_lds[16 + r][c] = f2bf(fmaxf(acc1[i] + bias, 0.f));
        }
    }
    __syncthreads();

    // ---------- Phase C: tower via MFMA over all 4 domains (waves 0..3) ----------
    // h_all[32 rows][32 cols], col = d*8 + tt.  wave w: mtile = w>>1, ntile = w&1
    if (w < 4) {
        const int mt = w >> 1;
        const int nt = w & 1;
        f32x4 acc = {0.f,0.f,0.f,0.f};
        const bf16x8* wsT1v = reinterpret_cast<const bf16x8*>(wsT1);
#pragma unroll
        for (int ks2 = 0; ks2 < 4; ++ks2) {
            const bf16x8 a = *reinterpret_cast<const bf16x8*>(
                &feat_lds[(mt << 4) + llo][(ks2 << 5) + (lhi << 3)]);
            const bf16x8 b = wsT1v[((ks2 << 1) + nt) * 64 + l];
            acc = __builtin_amdgcn_mfma_f32_16x16x32_bf16(a, b, acc, 0, 0, 0);
        }
        const int col    = (nt << 4) + llo;    // global tower col = d*8 + tt
        const float b1v  = tower_b1[col];
        const float w2v  = tower_W2[col];
        const int  dlane = (nt << 1) + (llo >> 3);
        const bool writer = ((llo & 7) == 0);
#pragma unroll
        for (int i = 0; i < 4; ++i) {
            float v = fmaxf(acc[i] + b1v, 0.f) * w2v;
            v += __shfl_xor(v, 1);
            v += __shfl_xor(v, 2);
            v += __shfl_xor(v, 4);
            if (writer) {
                const int r   = (mt << 4) + (lhi << 2) + i;
                const int d_r = domain_id[r0 + r];
                if (d_r == dlane) {
                    out[r0 + r] = 1.f / (1.f + expf(-(v + tower_b2[d_r])));
                }
            }
        }
    }
}

extern "C" void kernel_launch(void* const* d_in, const int* in_sizes, int n_in,
                              void* d_out, int out_size, void* d_ws, size_t ws_size,
                              hipStream_t stream) {
    const int*   sparse_ids = (const int*)  d_in[0];
    const float* dense      = (const float*)d_in[1];
    const int*   domain_id  = (const int*)  d_in[2];
    const float* emb_tables = (const float*)d_in[3];
    const float* W_bottom   = (const float*)d_in[4];
    const float* b_bottom   = (const float*)d_in[5];
    const float* tower_W1   = (const float*)d_in[6];
    const float* tower_b1   = (const float*)d_in[7];
    const float* tower_W2   = (const float*)d_in[8];
    const float* tower_b2   = (const float*)d_in[9];
    float* out = (float*)d_out;

    unsigned short* wsB  = (unsigned short*)d_ws;                    // 114,688 B
    unsigned short* wsT1 = (unsigned short*)((char*)d_ws + 131072);  //   8,192 B

    // prep: 7168 (W_bottom pack) + 512 (tower_W1 pack) threads
    prep_kernel<<<(NKS * 8 * 64 + 8 * 64 + 255) / 256, 256, 0, stream>>>(
        W_bottom, tower_W1, wsB, wsT1);

    sb_fused_kernel<<<B_ / BB, NT, 0, stream>>>(
        sparse_ids, dense, domain_id, emb_tables,
        b_bottom, tower_b1, tower_W2, tower_b2, wsB, wsT1, out);
}

// Round 7
// 24.196 us; speedup vs baseline: 2.4206x; 1.0532x over previous
//
#include <hip/hip_runtime.h>
#include <math.h>

// Problem dims (fixed by the reference)
#define F_  26
#define V_  100000
#define E_  16
#define B_  16384
#define ND_ 13
#define D_  4
#define H_  128
#define T_  8
#define KP  448      // K padded to 14*32
#define NKS 14       // K-steps of 32
#define NPRE 7       // B-fragments preloaded to registers before Phase A
#define XSTR 456     // x_lds row stride in bf16 (448 + 8 pad)
#define FSTR 136     // feat_lds row stride in bf16 (128 + 8 pad)
#define BB  32       // batch rows per block
#define NT  512      // threads per block
#define NGT 7        // gather tasks per thread (ceil(3328/512))

typedef short bf16x8 __attribute__((ext_vector_type(8)));
typedef float f32x4  __attribute__((ext_vector_type(4)));

__device__ __forceinline__ unsigned short f2bf(float f) {
    unsigned int u = __float_as_uint(f);
    u += 0x7FFF + ((u >> 16) & 1);   // RNE
    return (unsigned short)(u >> 16);
}

// ---------- prep: pack W_bottom + tower_W1 into bf16 MFMA B-fragments ----------
// wsB: fragment (ks, n): lane l elem j = W[ks*32 + (l>>4)*8 + j][n*16 + (l&15)]
// wsT1: fragment (ks2, n2): lane l elem j = W1_all[ks2*32 + (l>>4)*8 + j][n2*16 + (l&15)]
//   where W1_all[h][d*8+tt] = tower_W1[d][h][tt]
__global__ __launch_bounds__(256)
void prep_kernel(const float* __restrict__ W_bottom,
                 const float* __restrict__ tower_W1,
                 unsigned short* __restrict__ wsB,
                 unsigned short* __restrict__ wsT1)
{
    const int tid = blockIdx.x * 256 + threadIdx.x;
    if (tid < NKS * 8 * 64) {
        const int s   = tid >> 9;        // k-step
        const int rem = tid & 511;
        const int n   = rem >> 6;        // ntile
        const int l   = rem & 63;        // lane
        const int kbase = s * 32 + ((l >> 4) << 3);
        const int col   = (n << 4) + (l & 15);
        unsigned long long lo = 0, hi = 0;
#pragma unroll
        for (int j = 0; j < 4; ++j) {
            const int k = kbase + j;
            const float f = (k < 429) ? W_bottom[k * H_ + col] : 0.f;
            lo |= (unsigned long long)f2bf(f) << (16 * j);
        }
#pragma unroll
        for (int j = 0; j < 4; ++j) {
            const int k = kbase + 4 + j;
            const float f = (k < 429) ? W_bottom[k * H_ + col] : 0.f;
            hi |= (unsigned long long)f2bf(f) << (16 * j);
        }
        ulonglong2 pack; pack.x = lo; pack.y = hi;
        *reinterpret_cast<ulonglong2*>(wsB + (size_t)tid * 8) = pack;
    } else {
        const int t2 = tid - NKS * 8 * 64;
        if (t2 < 8 * 64) {               // 4 ks2 x 2 n2 fragments
            const int frag = t2 >> 6;    // ks2*2 + n2
            const int l    = t2 & 63;
            const int ks2  = frag >> 1;
            const int n2   = frag & 1;
            const int kbase = ks2 * 32 + ((l >> 4) << 3);
            const int col   = (n2 << 4) + (l & 15);
            const int d     = col >> 3;
            const int tt    = col & 7;
            unsigned long long lo = 0, hi = 0;
#pragma unroll
            for (int j = 0; j < 4; ++j) {
                const int h = kbase + j;
                lo |= (unsigned long long)f2bf(tower_W1[((d << 7) + h) * T_ + tt]) << (16 * j);
            }
#pragma unroll
            for (int j = 0; j < 4; ++j) {
                const int h = kbase + 4 + j;
                hi |= (unsigned long long)f2bf(tower_W1[((d << 7) + h) * T_ + tt]) << (16 * j);
            }
            ulonglong2 pack; pack.x = lo; pack.y = hi;
            *reinterpret_cast<ulonglong2*>(wsT1 + (size_t)t2 * 8) = pack;
        }
    }
}

// ---------- fused main kernel ----------
__global__ __launch_bounds__(NT, 4)
void sb_fused_kernel(const int* __restrict__ sparse_ids,
                     const float* __restrict__ dense,
                     const int* __restrict__ domain_id,
                     const float* __restrict__ emb_tables,
                     const float* __restrict__ b_bottom,
                     const float* __restrict__ tower_b1,
                     const float* __restrict__ tower_W2,
                     const float* __restrict__ tower_b2,
                     const unsigned short* __restrict__ wsB,
                     const unsigned short* __restrict__ wsT1,
                     float* __restrict__ out)
{
    __shared__ unsigned short x_lds[BB][XSTR];     // 29,184 B
    __shared__ unsigned short feat_lds[BB][FSTR];  //  8,704 B

    const int t  = threadIdx.x;
    const int r0 = blockIdx.x * BB;
    const int l   = t & 63;
    const int w   = t >> 6;        // 0..7
    const int lhi = l >> 4;        // 0..3
    const int llo = l & 15;

    const bf16x8* wsBv = reinterpret_cast<const bf16x8*>(wsB);

    // ---------- Preload: first NPRE B-fragments for this wave's ntile ----------
    // Issued before the gather so their L2/HBM latency hides under Phase A.
    bf16x8 bf_pre[NPRE];
#pragma unroll
    for (int ks = 0; ks < NPRE; ++ks) {
        bf_pre[ks] = wsBv[((ks << 3) + w) * 64 + l];
    }

    // ---------- Phase A: hand-pipelined gather (fp32 -> bf16) into LDS ----------
    // 32 rows * 26 fields * 4 quarters = 3328 float4-tasks; 4 lanes share one row.
    {
        int    ldsoff[NGT];
        int    id_[NGT];
        int    fq_[NGT];
        float4 v_[NGT];
#pragma unroll
        for (int it = 0; it < NGT; ++it) {
            const int idx = t + (it << 9);
            if (idx < BB * F_ * 4) {
                const int q   = idx & 3;
                const int rf  = idx >> 2;          // row * F_ + f
                const int row = rf / F_;
                const int f   = rf - row * F_;
                id_[it]    = sparse_ids[(r0 + row) * F_ + f];
                fq_[it]    = (f << 2) | q;
                ldsoff[it] = row * XSTR + (f << 4) + (q << 2);
            }
        }
#pragma unroll
        for (int it = 0; it < NGT; ++it) {
            const int idx = t + (it << 9);
            if (idx < BB * F_ * 4) {
                const int f = fq_[it] >> 2;
                const int q = fq_[it] & 3;
                v_[it] = *reinterpret_cast<const float4*>(
                    emb_tables + ((size_t)f * V_ + (size_t)id_[it]) * E_ + (q << 2));
            }
        }
#pragma unroll
        for (int it = 0; it < NGT; ++it) {
            const int idx = t + (it << 9);
            if (idx < BB * F_ * 4) {
                ushort4 b;
                b.x = f2bf(v_[it].x); b.y = f2bf(v_[it].y);
                b.z = f2bf(v_[it].z); b.w = f2bf(v_[it].w);
                *reinterpret_cast<ushort4*>(&x_lds[0][0] + ldsoff[it]) = b;
            }
        }
    }
    // dense -> cols 416..428 (bf16), zero-pad cols 429..447 (2 tasks/thread)
#pragma unroll
    for (int it = 0; it < 2; ++it) {
        const int idx = t + (it << 9);
        const int row = idx >> 5;
        const int c   = 416 + (idx & 31);
        x_lds[row][c] = (c < 429) ? f2bf(dense[(r0 + row) * ND_ + (c - 416)]) : 0;
    }
    __syncthreads();

    // ---------- Phase B: bottom GEMM via MFMA  feat = relu(X @ W + b) ----------
    // 8 waves: wave w owns ntile w (cols 16w..16w+15), both mtiles (rows 0..31)
    f32x4 acc0 = {0.f,0.f,0.f,0.f};
    f32x4 acc1 = acc0;

#pragma unroll
    for (int ks = 0; ks < NKS; ++ks) {
        const int ko = ks * 32 + (lhi << 3);
        const bf16x8 a0 = *reinterpret_cast<const bf16x8*>(&x_lds[llo][ko]);
        const bf16x8 a1 = *reinterpret_cast<const bf16x8*>(&x_lds[16 + llo][ko]);
        const bf16x8 b  = (ks < NPRE) ? bf_pre[ks] : wsBv[((ks << 3) + w) * 64 + l];
        acc0 = __builtin_amdgcn_mfma_f32_16x16x32_bf16(a0, b, acc0, 0, 0, 0);
        acc1 = __builtin_amdgcn_mfma_f32_16x16x32_bf16(a1, b, acc1, 0, 0, 0);
    }

    {   // epilogue: bias + relu -> feat_lds (bf16, A-fragment-friendly layout)
        const int c = (w << 4) + llo;
        const float bias = b_bottom[c];
#pragma unroll
        for (int i = 0; i < 4; ++i) {
            const int r = (lhi << 2) + i;
            feat_lds[r][c]      = f2bf(fmaxf(acc0[i] + bias, 0.f));
            feat_lds[16 + r][c] = f2bf(fmaxf(acc1[i] + bias, 0.f));
        }
    }
    __syncthreads();

    // ---------- Phase C: tower via MFMA over all 4 domains (waves 0..3) ----------
    // h_all[32 rows][32 cols], col = d*8 + tt.  wave w: mtile = w>>1, ntile = w&1
    if (w < 4) {
        const int mt = w >> 1;
        const int nt = w & 1;
        f32x4 acc = {0.f,0.f,0.f,0.f};
        const bf16x8* wsT1v = reinterpret_cast<const bf16x8*>(wsT1);
#pragma unroll
        for (int ks2 = 0; ks2 < 4; ++ks2) {
            const bf16x8 a = *reinterpret_cast<const bf16x8*>(
                &feat_lds[(mt << 4) + llo][(ks2 << 5) + (lhi << 3)]);
            const bf16x8 b = wsT1v[((ks2 << 1) + nt) * 64 + l];
            acc = __builtin_amdgcn_mfma_f32_16x16x32_bf16(a, b, acc, 0, 0, 0);
        }
        const int col    = (nt << 4) + llo;    // global tower col = d*8 + tt
        const float b1v  = tower_b1[col];
        const float w2v  = tower_W2[col];
        const int  dlane = (nt << 1) + (llo >> 3);
        const bool writer = ((llo & 7) == 0);
#pragma unroll
        for (int i = 0; i < 4; ++i) {
            float v = fmaxf(acc[i] + b1v, 0.f) * w2v;
            v += __shfl_xor(v, 1);
            v += __shfl_xor(v, 2);
            v += __shfl_xor(v, 4);
            if (writer) {
                const int r   = (mt << 4) + (lhi << 2) + i;
                const int d_r = domain_id[r0 + r];
                if (d_r == dlane) {
                    out[r0 + r] = 1.f / (1.f + expf(-(v + tower_b2[d_r])));
                }
            }
        }
    }
}

extern "C" void kernel_launch(void* const* d_in, const int* in_sizes, int n_in,
                              void* d_out, int out_size, void* d_ws, size_t ws_size,
                              hipStream_t stream) {
    const int*   sparse_ids = (const int*)  d_in[0];
    const float* dense      = (const float*)d_in[1];
    const int*   domain_id  = (const int*)  d_in[2];
    const float* emb_tables = (const float*)d_in[3];
    const float* W_bottom   = (const float*)d_in[4];
    const float* b_bottom   = (const float*)d_in[5];
    const float* tower_W1   = (const float*)d_in[6];
    const float* tower_b1   = (const float*)d_in[7];
    const float* tower_W2   = (const float*)d_in[8];
    const float* tower_b2   = (const float*)d_in[9];
    float* out = (float*)d_out;

    unsigned short* wsB  = (unsigned short*)d_ws;                    // 114,688 B
    unsigned short* wsT1 = (unsigned short*)((char*)d_ws + 131072);  //   8,192 B

    // prep: 7168 (W_bottom pack) + 512 (tower_W1 pack) threads
    prep_kernel<<<(NKS * 8 * 64 + 8 * 64 + 255) / 256, 256, 0, stream>>>(
        W_bottom, tower_W1, wsB, wsT1);

    sb_fused_kernel<<<B_ / BB, NT, 0, stream>>>(
        sparse_ids, dense, domain_id, emb_tables,
        b_bottom, tower_b1, tower_W2, tower_b2, wsB, wsT1, out);
}